// Round 5
// baseline (828.505 us; speedup 1.0000x reference)
//
#include <hip/hip_runtime.h>

#define BS 1024
#define TS 64

__device__ __forceinline__ float sigf_p(float x){ return 1.f/(1.f+expf(-x)); }
__device__ __forceinline__ float sigf(float x){ return 1.f/(1.f+__expf(-x)); }
__device__ __forceinline__ float tanh_fast(float x){
  float cx = fminf(fmaxf(x,-15.f),15.f);
  float e = __expf(2.f*cx);
  return (e-1.f)/(e+1.f);
}
__device__ __forceinline__ float lrelu(float v){ return v>=0.f ? v : 0.1f*v; }
__device__ __forceinline__ float dot4(float4 a, float4 b){
  return a.x*b.x + a.y*b.y + a.z*b.z + a.w*b.w;
}
__device__ __forceinline__ float rdlane(float v, int k){
  return __int_as_float(__builtin_amdgcn_readlane(__float_as_int(v), k));
}

// ---------------- Kernel A: batch-independent precompute (unchanged) ----------------
__global__ __launch_bounds__(256) void precompute_kernel(
    const float* __restrict__ Whh_t, const float* __restrict__ bih_t,
    const float* __restrict__ bhh_t,
    const float* __restrict__ Wof,  const float* __restrict__ bof,
    const float* __restrict__ Wtf,  const float* __restrict__ btf,
    const float* __restrict__ Wmix, const float* __restrict__ bmix,
    float* __restrict__ ws_wcomb, float* __restrict__ ws_mbias)
{
  __shared__ __align__(16) float sHall[TS*64];
  __shared__ __align__(16) float sTs[TS*64];
  __shared__ float sWof[64*64];
  __shared__ float sG[256];
  __shared__ float sBof[64];
  __shared__ float sCmr[64];

  const int t = threadIdx.x;

  float4 wrow[16];
#pragma unroll
  for (int j=0;j<16;++j) wrow[j] = reinterpret_cast<const float4*>(Whh_t + t*64)[j];
  const float btr = bih_t[t] + bhh_t[t];

  for (int i=t;i<4096;i+=256) sWof[i] = Wof[i];
  if (t<64) sBof[t] = bof[t];
  __syncthreads();

  float c_reg = 0.f;
  for (int s=0;s<TS;++s){
    float a0=btr, a1=0.f, a2=0.f, a3=0.f;
    if (s>0){
      const float4* h4 = reinterpret_cast<const float4*>(sHall + (s-1)*64);
#pragma unroll
      for (int j=0;j<16;j+=4){
        a0 += dot4(wrow[j],   h4[j]);
        a1 += dot4(wrow[j+1], h4[j+1]);
        a2 += dot4(wrow[j+2], h4[j+2]);
        a3 += dot4(wrow[j+3], h4[j+3]);
      }
    }
    sG[t] = (a0+a1)+(a2+a3);
    __syncthreads();
    if (t<64){
      float gi=sG[t], gf=sG[64+t], gg=sG[128+t], go=sG[192+t];
      c_reg = sigf_p(gf)*c_reg + sigf_p(gi)*tanhf(gg);
      sHall[s*64+t] = sigf_p(go)*tanhf(c_reg);
    }
    __syncthreads();
  }

  if (t<64){
    float acc = bmix[t];
    for (int k=0;k<64;++k) acc += Wmix[t*128+64+k]*sBof[k];
    sCmr[t] = acc;
  }
  for (int o=t;o<TS*64;o+=256){
    int s=o>>6, i=o&63;
    float acc = btf[i];
    for (int k=0;k<64;++k) acc += Wtf[i*64+k]*sHall[s*64+k];
    sTs[o] = acc;
  }
  for (int o=t;o<4096;o+=256){
    int r=o>>6, j=o&63;
    float acc = 0.f;
    for (int k=0;k<64;++k) acc += Wmix[r*128+64+k]*sWof[k*64+j];
    ws_wcomb[o] = acc;
  }
  __syncthreads();
  for (int o=t;o<TS*64;o+=256){
    int s=o>>6, j=o&63;
    float acc = sCmr[j];
    for (int k=0;k<64;++k) acc += Wmix[j*128+k]*sTs[s*64+k];
    ws_mbias[o] = acc;
  }
}

// ---------------- Kernel B: pipelined — waves0-3 gate matvec, wave4 serial tail ----------------
__global__ __launch_bounds__(320, 3) void main_kernel(
    const float* __restrict__ obsv,
    const float* __restrict__ Wih_o, const float* __restrict__ Whh_o,
    const float* __restrict__ bih_o, const float* __restrict__ bhh_o,
    const float* __restrict__ W1, const float* __restrict__ b1,
    const float* __restrict__ W2, const float* __restrict__ b2,
    const float* __restrict__ W3, const float* __restrict__ b3,
    const float* __restrict__ wcomb, const float* __restrict__ mbias,
    float* __restrict__ out)
{
  __shared__ __align__(16) float4 sWc[64*17];   // Wcomb rows, padded 16->17 float4
  __shared__ __align__(16) float4 sW1[32*17];   // W1 rows (16 f4) padded to 17
  __shared__ __align__(16) float4 sW2[32*9];    // W2 rows (8 f4) padded to 9
  __shared__ __align__(16) float sMb[TS*64];
  __shared__ float sG[256];
  __shared__ __align__(16) float sH[64];
  __shared__ __align__(16) float sM[64];
  __shared__ __align__(16) float sA1[32];
  __shared__ float sObs[16];

  const int t   = threadIdx.x;
  const int blk = blockIdx.x;

  // ---- staging ----
  for (int i=t; i<64*16; i+=320){
    int row=i>>4, q=i&15;
    sWc[row*17+q] = reinterpret_cast<const float4*>(wcomb)[i];
  }
  for (int i=t; i<32*16; i+=320){
    int row=i>>4, q=i&15;
    sW1[row*17+q] = reinterpret_cast<const float4*>(W1)[i];
  }
  for (int i=t; i<32*8; i+=320){
    int row=i>>3, q=i&7;
    sW2[row*9+q] = reinterpret_cast<const float4*>(W2)[i];
  }
  for (int i=t; i<TS*16; i+=320)
    reinterpret_cast<float4*>(sMb)[i] = reinterpret_cast<const float4*>(mbias)[i];
  if (t<16) sObs[t] = obsv[blk*16+t];
  if (t<64) sH[t] = 0.f;

  // ---- role-specific registers ----
  // waves 0-3 (t<256): split-K gate matvec. thread = (w, l=4r+c): rows w*64+16p+r, k in [16c,16c+16)
  float4 wsp[4][4];
  float  wih0[4], wih1[4], bsum[4];
  int w=0, r=0, c=0;
  // wave 4 (t>=256): serial tail. lane l = hidden unit j.
  float wihr[4][2];
  float4 w3b;           // {w3c0, w3c1, b1r, b2r}
  float b30=0.f, b31=0.f;
  float bl00=0,bl01=0,bl10=0,bl11=0,bl20=0,bl21=0;
  int lane=0, rr=0, hf=0;

  if (t < 256){
    w = t>>6; int l = t&63; r = l>>2; c = l&3;
#pragma unroll
    for (int p=0;p<4;++p){
      const int row = w*64 + p*16 + r;
      const float4* base = reinterpret_cast<const float4*>(Whh_o + row*64 + c*16);
#pragma unroll
      for (int q=0;q<4;++q) wsp[p][q] = base[q];
      wih0[p] = Wih_o[row*2];
      wih1[p] = Wih_o[row*2+1];
      bsum[p] = bih_o[row] + bhh_o[row];
    }
  } else {
    lane = t-256; rr = lane&31; hf = lane>>5;
#pragma unroll
    for (int g=0;g<4;++g){
      wihr[g][0] = Wih_o[(g*64+lane)*2];
      wihr[g][1] = Wih_o[(g*64+lane)*2+1];
    }
    w3b = make_float4(W3[rr], W3[32+rr], b1[rr], b2[rr]);
    b30 = b3[0]; b31 = b3[1];
    bl00 = obsv[blk*16+10]; bl01 = obsv[blk*16+11];
    bl10 = obsv[blk*16+12]; bl11 = obsv[blk*16+13];
    bl20 = obsv[blk*16+14]; bl21 = obsv[blk*16+15];
    out[BS*TS*2 + blk*64 + lane] = 0.f;   // c_out zeros
  }
  __syncthreads();

  float c_reg = 0.f, hreg = 0.f, y0r = 0.f, y1r = 0.f;
  const float4* sH4  = reinterpret_cast<const float4*>(sH);
  const float4* sM4  = reinterpret_cast<const float4*>(sM);
  const float4* sA14 = reinterpret_cast<const float4*>(sA1);

  // 71 LSTM cell steps: it=0..7 warmup (x=obs), it=8..70 feedback (x=y). Tail runs for it>=7.
  for (int it=0; it<71; ++it){
    // ---- phase A (waves 0-3): gH = b + Whh·h  (+ Wih·x during warmup) ----
    if (t < 256){
      float pacc[4];
#pragma unroll
      for (int p=0;p<4;++p){
        float4 h0 = sH4[c*4+0], h1 = sH4[c*4+1], h2 = sH4[c*4+2], h3 = sH4[c*4+3];
        pacc[p] = dot4(wsp[p][0],h0) + dot4(wsp[p][1],h1)
                + dot4(wsp[p][2],h2) + dot4(wsp[p][3],h3);
      }
#pragma unroll
      for (int p=0;p<4;++p){
        pacc[p] += __shfl_xor(pacc[p], 1);
        pacc[p] += __shfl_xor(pacc[p], 2);
      }
      if (c == 0){
        float x0=0.f, x1=0.f;
        if (it < 8){ x0 = sObs[2*it]; x1 = sObs[2*it+1]; }
#pragma unroll
        for (int p=0;p<4;++p){
          float g = pacc[p] + bsum[p];
          if (it < 8) g += wih0[p]*x0 + wih1[p]*x1;
          sG[w*64 + p*16 + r] = g;
        }
      }
    }
    __syncthreads();   // B1: sG ready

    // ---- phase B (wave 4): finish gates with y, cell update ----
    if (t >= 256){
      float g0 = sG[lane], g1 = sG[64+lane], g2 = sG[128+lane], g3 = sG[192+lane];
      if (it >= 8){
        g0 += wihr[0][0]*y0r + wihr[0][1]*y1r;
        g1 += wihr[1][0]*y0r + wihr[1][1]*y1r;
        g2 += wihr[2][0]*y0r + wihr[2][1]*y1r;
        g3 += wihr[3][0]*y0r + wihr[3][1]*y1r;
      }
      c_reg = sigf(g1)*c_reg + sigf(g0)*tanh_fast(g2);
      hreg  = sigf(g3)*tanh_fast(c_reg);
      sH[lane] = hreg;
    }
    __syncthreads();   // B2: sH ready -> waves0-3 start next matvec; wave4 runs tail

    // ---- phase C (wave 4): tail -> y ----
    if (t >= 256 && it >= 7){
      const int i = it - 7;
      // mix: m[lane] = Wc[lane,:]·h + mbias[i][lane]   (h broadcast via readlane)
      float acc = sMb[i*64 + lane];
#pragma unroll
      for (int q=0;q<16;++q){
        float4 wc = sWc[lane*17 + q];
        acc = fmaf(wc.x, rdlane(hreg, 4*q+0), acc);
        acc = fmaf(wc.y, rdlane(hreg, 4*q+1), acc);
        acc = fmaf(wc.z, rdlane(hreg, 4*q+2), acc);
        acc = fmaf(wc.w, rdlane(hreg, 4*q+3), acc);
      }
      sM[lane] = acc;
      __builtin_amdgcn_wave_barrier();
      // MLP1 (32x64): row rr, k-half hf
      float a1 = 0.f;
#pragma unroll
      for (int q=0;q<8;++q) a1 += dot4(sW1[rr*17 + hf*8 + q], sM4[hf*8 + q]);
      a1 += __shfl_xor(a1, 32);
      if (lane < 32) sA1[lane] = lrelu(a1 + w3b.z);
      __builtin_amdgcn_wave_barrier();
      // MLP2 (32x32): row rr, k-half hf
      float a2 = 0.f;
#pragma unroll
      for (int q=0;q<4;++q) a2 += dot4(sW2[rr*9 + hf*4 + q], sA14[hf*4 + q]);
      a2 += __shfl_xor(a2, 32);
      a2 = lrelu(a2 + w3b.w);
      // head (2x32): butterfly over each 32-lane group (groups are duplicates)
      float p0 = a2*w3b.x, p1 = a2*w3b.y;
#pragma unroll
      for (int m=1; m<=16; m<<=1){
        p0 += __shfl_xor(p0, m);
        p1 += __shfl_xor(p1, m);
      }
      const float yn0 = p0 + b30 + bl20 + (bl20 - bl00)*0.5f;
      const float yn1 = p1 + b31 + bl21 + (bl21 - bl01)*0.5f;
      bl00 = bl10; bl01 = bl11;
      bl10 = bl20; bl11 = bl21;
      bl20 = yn0;  bl21 = yn1;
      y0r = yn0; y1r = yn1;
      if (lane == 0){
        float2 o2 = make_float2(yn0, yn1);
        *reinterpret_cast<float2*>(out + (size_t)(blk*TS + i)*2) = o2;
      }
    }
  }
}

extern "C" void kernel_launch(void* const* d_in, const int* in_sizes, int n_in,
                              void* d_out, int out_size, void* d_ws, size_t ws_size,
                              hipStream_t stream)
{
  const float* obsv  = (const float*)d_in[0];
  // d_in[1] = teom : never used (teom-LSTM input is zeros)
  const float* Wih_o = (const float*)d_in[2];
  const float* Whh_o = (const float*)d_in[3];
  const float* bih_o = (const float*)d_in[4];
  const float* bhh_o = (const float*)d_in[5];
  // d_in[6] = Wih_t : multiplies zeros, unused
  const float* Whh_t = (const float*)d_in[7];
  const float* bih_t = (const float*)d_in[8];
  const float* bhh_t = (const float*)d_in[9];
  const float* Wof   = (const float*)d_in[10];
  const float* bof   = (const float*)d_in[11];
  const float* Wtf   = (const float*)d_in[12];
  const float* btf   = (const float*)d_in[13];
  const float* Wmix  = (const float*)d_in[14];
  const float* bmix  = (const float*)d_in[15];
  const float* W1    = (const float*)d_in[16];
  const float* b1    = (const float*)d_in[17];
  const float* W2    = (const float*)d_in[18];
  const float* b2    = (const float*)d_in[19];
  const float* W3    = (const float*)d_in[20];
  const float* b3    = (const float*)d_in[21];

  float* wsf = (float*)d_ws;   // [0,4096): Wcomb   [4096,8192): mbias

  precompute_kernel<<<1,256,0,stream>>>(Whh_t,bih_t,bhh_t,Wof,bof,Wtf,btf,
                                        Wmix,bmix, wsf, wsf+4096);
  main_kernel<<<BS,320,0,stream>>>(obsv,Wih_o,Whh_o,bih_o,bhh_o,
                                   W1,b1,W2,b2,W3,b3,
                                   wsf, wsf+4096,
                                   (float*)d_out);
}

// Round 6
// 586.291 us; speedup vs baseline: 1.4131x; 1.4131x over previous
//
#include <hip/hip_runtime.h>

#define BS 1024
#define TS 64

__device__ __forceinline__ float sigf(float x){ return 1.f/(1.f+__expf(-x)); }
__device__ __forceinline__ float tanh_fast(float x){
  float cx = fminf(fmaxf(x,-15.f),15.f);
  float e = __expf(2.f*cx);
  return (e-1.f)/(e+1.f);
}
__device__ __forceinline__ float lrelu(float v){ return v>=0.f ? v : 0.1f*v; }
__device__ __forceinline__ float dot4(float4 a, float4 b){
  return a.x*b.x + a.y*b.y + a.z*b.z + a.w*b.w;
}

// ---------------- Kernel A: batch-independent precompute ----------------
// ws_wcomb[64*64] = Wmix[:,64:] @ Wof
// ws_mbias[TS*64] : per-step mix bias (teom LSTM + Wtf + Wmix1 folded)
__global__ __launch_bounds__(256) void precompute_kernel(
    const float* __restrict__ Whh_t, const float* __restrict__ bih_t,
    const float* __restrict__ bhh_t,
    const float* __restrict__ Wof,  const float* __restrict__ bof,
    const float* __restrict__ Wtf,  const float* __restrict__ btf,
    const float* __restrict__ Wmix, const float* __restrict__ bmix,
    float* __restrict__ ws_wcomb, float* __restrict__ ws_mbias)
{
  __shared__ __align__(16) float sHall[TS*64];
  __shared__ __align__(16) float sTs[TS*64];
  __shared__ float sWof[64*64];
  __shared__ float sG[256];
  __shared__ float sBof[64];
  __shared__ float sCmr[64];

  const int t = threadIdx.x;

  float4 wrow[16];
#pragma unroll
  for (int j=0;j<16;++j) wrow[j] = reinterpret_cast<const float4*>(Whh_t + t*64)[j];
  const float btr = bih_t[t] + bhh_t[t];

  for (int i=t;i<4096;i+=256) sWof[i] = Wof[i];
  if (t<64) sBof[t] = bof[t];
  __syncthreads();

  float c_reg = 0.f;
  for (int s=0;s<TS;++s){
    float a0=btr, a1=0.f, a2=0.f, a3=0.f;
    if (s>0){
      const float4* h4 = reinterpret_cast<const float4*>(sHall + (s-1)*64);
#pragma unroll
      for (int j=0;j<16;j+=4){
        a0 += dot4(wrow[j],   h4[j]);
        a1 += dot4(wrow[j+1], h4[j+1]);
        a2 += dot4(wrow[j+2], h4[j+2]);
        a3 += dot4(wrow[j+3], h4[j+3]);
      }
    }
    sG[t] = (a0+a1)+(a2+a3);
    __syncthreads();
    if (t<64){
      float gi=sG[t], gf=sG[64+t], gg=sG[128+t], go=sG[192+t];
      c_reg = sigf(gf)*c_reg + sigf(gi)*tanh_fast(gg);
      sHall[s*64+t] = sigf(go)*tanh_fast(c_reg);
    }
    __syncthreads();
  }

  if (t<64){
    float acc = bmix[t];
    for (int k=0;k<64;++k) acc += Wmix[t*128+64+k]*sBof[k];
    sCmr[t] = acc;
  }
  for (int o=t;o<TS*64;o+=256){
    int s=o>>6, i=o&63;
    float acc = btf[i];
    for (int k=0;k<64;++k) acc += Wtf[i*64+k]*sHall[s*64+k];
    sTs[o] = acc;
  }
  for (int o=t;o<4096;o+=256){
    int r=o>>6, j=o&63;
    float acc = 0.f;
    for (int k=0;k<64;++k) acc += Wmix[r*128+64+k]*sWof[k*64+j];
    ws_wcomb[o] = acc;
  }
  __syncthreads();
  for (int o=t;o<TS*64;o+=256){
    int s=o>>6, j=o&63;
    float acc = sCmr[j];
    for (int k=0;k<64;++k) acc += Wmix[j*128+k]*sTs[s*64+k];
    ws_mbias[o] = acc;
  }
}

// ---------------- Kernel B: 2 batch/block, 256 thr, wave-local tails, 2 barriers/step ----------------
__global__ __launch_bounds__(256, 2) void main_kernel(
    const float* __restrict__ obsv,
    const float* __restrict__ Wih_o, const float* __restrict__ Whh_o,
    const float* __restrict__ bih_o, const float* __restrict__ bhh_o,
    const float* __restrict__ W1, const float* __restrict__ b1,
    const float* __restrict__ W2, const float* __restrict__ b2,
    const float* __restrict__ W3, const float* __restrict__ b3,
    const float* __restrict__ wcomb, const float* __restrict__ mbias,
    float* __restrict__ out)
{
  __shared__ __align__(16) float4 sWc[16*64];  // [q][row] 16 KB
  __shared__ __align__(16) float4 sW1[16*32];  // [q][row] 8 KB
  __shared__ __align__(16) float4 sW2[8*32];   // [q][row] 4 KB
  __shared__ float sG[2*256];
  __shared__ __align__(16) float sH[2*64];
  __shared__ __align__(16) float sM[2*64];
  __shared__ __align__(16) float sA1[2*32];
  __shared__ float sY[2*2];
  __shared__ float sObs[2*16];

  const int t    = threadIdx.x;
  const int blk  = blockIdx.x;
  const int lane = t & 63;
  const int w    = t >> 6;
  const bool tailw = (w < 2);

  if (t < 128) out[BS*TS*2 + blk*128 + t] = 0.f;   // c_out zeros

  // gate row t (both batches share these weights -> 2-acc ILP)
  float4 wrow[16];
#pragma unroll
  for (int j=0;j<16;++j) wrow[j] = reinterpret_cast<const float4*>(Whh_o + t*64)[j];
  const float wi0  = Wih_o[2*t];
  const float wi1  = Wih_o[2*t+1];
  const float b_or = bih_o[t] + bhh_o[t];

  // staging (row->[q][row] transposed-packed)
  for (int i=t;i<1024;i+=256) sWc[i] = reinterpret_cast<const float4*>(wcomb)[(i&63)*16 + (i>>6)];
  for (int i=t;i<512;i+=256)  sW1[i] = reinterpret_cast<const float4*>(W1)[(i&31)*16 + (i>>5)];
  if (t<256)                  sW2[t] = reinterpret_cast<const float4*>(W2)[(t&31)*8 + (t>>5)];
  if (t<32)  sObs[t] = obsv[blk*32 + t];
  if (t<128) sH[t] = 0.f;
  __syncthreads();

  // tail-wave constants (waves 0,1; batch = w)
  const int rr = lane & 31, hf = lane >> 5;
  const float b1r = b1[rr], b2r = b2[rr];
  const float w30 = W3[rr], w31 = W3[32+rr];
  const float b30 = b3[0],  b31 = b3[1];
  float bl00=0,bl01=0,bl10=0,bl11=0,bl20=0,bl21=0;
  if (tailw){
    bl00 = sObs[w*16+10]; bl01 = sObs[w*16+11];
    bl10 = sObs[w*16+12]; bl11 = sObs[w*16+13];
    bl20 = sObs[w*16+14]; bl21 = sObs[w*16+15];
  }
  float c_reg = 0.f;

  const float4* sH4  = reinterpret_cast<const float4*>(sH);
  const float4* sM4  = reinterpret_cast<const float4*>(sM);
  const float4* sA14 = reinterpret_cast<const float4*>(sA1);

  // 71 LSTM steps: it 0..7 x=obs, it 8..70 x=y. Tail (mix->y) runs for it>=7.
  for (int it=0; it<71; ++it){
    // prefetch mbias for this step's tail (latency hidden under gate FMAs)
    float mb = 0.f;
    if (tailw && it >= 7) mb = mbias[(it-7)*64 + lane];

    // ---- phase A (all 4 waves): gates for both batches ----
    float x00,x01,x10,x11;
    if (it < 8){
      x00 = sObs[2*it];    x01 = sObs[2*it+1];
      x10 = sObs[16+2*it]; x11 = sObs[16+2*it+1];
    } else {
      x00 = sY[0]; x01 = sY[1]; x10 = sY[2]; x11 = sY[3];
    }
    float a0 = b_or + wi0*x00 + wi1*x01, p0 = 0.f;
    float a1 = b_or + wi0*x10 + wi1*x11, p1 = 0.f;
#pragma unroll
    for (int q=0;q<16;q+=2){
      const float4 wa = wrow[q], wb = wrow[q+1];
      a0 += dot4(wa, sH4[q]);      p0 += dot4(wb, sH4[q+1]);
      a1 += dot4(wa, sH4[16+q]);   p1 += dot4(wb, sH4[16+q+1]);
    }
    sG[t]     = a0 + p0;
    sG[256+t] = a1 + p1;
    __syncthreads();   // B1: sG ready

    // ---- tail (wave w handles batch w) ----
    if (tailw){
      const float g0 = sG[w*256+lane],     g1 = sG[w*256+64+lane];
      const float g2 = sG[w*256+128+lane], g3 = sG[w*256+192+lane];
      c_reg = sigf(g1)*c_reg + sigf(g0)*tanh_fast(g2);
      const float h = sigf(g3)*tanh_fast(c_reg);
      sH[w*64+lane] = h;
      __builtin_amdgcn_wave_barrier();

      if (it >= 7){
        const float4* sHw4 = reinterpret_cast<const float4*>(sH + w*64);
        // mix: m[lane] = Wc[lane,:]·h + mbias  (broadcast float4 h reads)
        float m0 = mb, m1 = 0.f, m2 = 0.f, m3 = 0.f;
#pragma unroll
        for (int q=0;q<16;q+=4){
          m0 += dot4(sWc[q*64+lane],     sHw4[q]);
          m1 += dot4(sWc[(q+1)*64+lane], sHw4[q+1]);
          m2 += dot4(sWc[(q+2)*64+lane], sHw4[q+2]);
          m3 += dot4(sWc[(q+3)*64+lane], sHw4[q+3]);
        }
        sM[w*64+lane] = (m0+m1)+(m2+m3);
        __builtin_amdgcn_wave_barrier();

        // MLP1 (32x64): row rr, k-half hf
        float u = 0.f;
#pragma unroll
        for (int q=0;q<8;++q) u += dot4(sW1[(hf*8+q)*32+rr], sM4[w*16 + hf*8 + q]);
        u += __shfl_xor(u, 32);
        if (lane < 32) sA1[w*32+lane] = lrelu(u + b1r);
        __builtin_amdgcn_wave_barrier();

        // MLP2 (32x32): row rr, k-half hf
        float v = 0.f;
#pragma unroll
        for (int q=0;q<4;++q) v += dot4(sW2[(hf*4+q)*32+rr], sA14[w*8 + hf*4 + q]);
        v += __shfl_xor(v, 32);
        const float a2v = lrelu(v + b2r);

        // head (2x32): butterfly over 32-lane halves (both halves duplicate)
        float q0 = a2v*w30, q1 = a2v*w31;
#pragma unroll
        for (int m=1;m<=16;m<<=1){
          q0 += __shfl_xor(q0, m);
          q1 += __shfl_xor(q1, m);
        }
        const float y0 = q0 + b30 + bl20 + (bl20 - bl00)*0.5f;
        const float y1 = q1 + b31 + bl21 + (bl21 - bl01)*0.5f;
        bl00 = bl10; bl01 = bl11;
        bl10 = bl20; bl11 = bl21;
        bl20 = y0;   bl21 = y1;
        if (lane == 0){
          sY[w*2+0] = y0; sY[w*2+1] = y1;
          *reinterpret_cast<float2*>(out + (size_t)((blk*2+w)*TS + (it-7))*2)
              = make_float2(y0, y1);
        }
      }
    }
    __syncthreads();   // B2: sH/sY ready for next gates
  }
}

extern "C" void kernel_launch(void* const* d_in, const int* in_sizes, int n_in,
                              void* d_out, int out_size, void* d_ws, size_t ws_size,
                              hipStream_t stream)
{
  const float* obsv  = (const float*)d_in[0];
  // d_in[1] = teom : never used (teom-LSTM input is zeros)
  const float* Wih_o = (const float*)d_in[2];
  const float* Whh_o = (const float*)d_in[3];
  const float* bih_o = (const float*)d_in[4];
  const float* bhh_o = (const float*)d_in[5];
  // d_in[6] = Wih_t : multiplies zeros, unused
  const float* Whh_t = (const float*)d_in[7];
  const float* bih_t = (const float*)d_in[8];
  const float* bhh_t = (const float*)d_in[9];
  const float* Wof   = (const float*)d_in[10];
  const float* bof   = (const float*)d_in[11];
  const float* Wtf   = (const float*)d_in[12];
  const float* btf   = (const float*)d_in[13];
  const float* Wmix  = (const float*)d_in[14];
  const float* bmix  = (const float*)d_in[15];
  const float* W1    = (const float*)d_in[16];
  const float* b1    = (const float*)d_in[17];
  const float* W2    = (const float*)d_in[18];
  const float* b2    = (const float*)d_in[19];
  const float* W3    = (const float*)d_in[20];
  const float* b3    = (const float*)d_in[21];

  float* wsf = (float*)d_ws;   // [0,4096): Wcomb   [4096,8192): mbias

  precompute_kernel<<<1,256,0,stream>>>(Whh_t,bih_t,bhh_t,Wof,bof,Wtf,btf,
                                        Wmix,bmix, wsf, wsf+4096);
  main_kernel<<<BS/2,256,0,stream>>>(obsv,Wih_o,Whh_o,bih_o,bhh_o,
                                     W1,b1,W2,b2,W3,b3,
                                     wsf, wsf+4096,
                                     (float*)d_out);
}